// Round 1
// baseline (918.106 us; speedup 1.0000x reference)
//
#include <hip/hip_runtime.h>

// ---------------------------------------------------------------------------
// FrozenSoftmaxAttention: B=4, L=4096, d=dv=dh=512
//   Qh = K@Wq^T, Kh = K@Wk^T, Vp = V@Wv^T
//   S = scale * Qh Kh^T, strict causal (j <= i-1), softmax, row0 zeroed
//   out = P@Vp ; Vhat = out@Wo^T  (fp32 output)
// Precision: hi/lo bf16 split (3-term MFMA) for QK path; plain bf16 elsewhere.
// ---------------------------------------------------------------------------

typedef unsigned short u16;
typedef short short8 __attribute__((ext_vector_type(8)));
typedef float floatx4 __attribute__((ext_vector_type(4)));

#define L_SEQ 4096
#define NBATCH 4
#define DMODEL 512
#define SCALE 0.22097086912079612f   // 5/sqrt(512)

__device__ __forceinline__ u16 f2bf(float f) {
  unsigned int u = __float_as_uint(f);
  u += 0x7fffu + ((u >> 16) & 1u);      // round-to-nearest-even
  return (u16)(u >> 16);
}
__device__ __forceinline__ float bf2f(u16 h) {
  return __uint_as_float(((unsigned int)h) << 16);
}

// ----------------- elementwise converts ------------------------------------
__global__ __launch_bounds__(256) void split_f32(const float* __restrict__ x,
                                                 u16* __restrict__ hi,
                                                 u16* __restrict__ lo, int n) {
  int i = blockIdx.x * 256 + threadIdx.x;
  if (i >= n) return;
  float f = x[i];
  u16 h = f2bf(f);
  hi[i] = h;
  lo[i] = f2bf(f - bf2f(h));
}

__global__ __launch_bounds__(256) void cvt_f32(const float* __restrict__ x,
                                               u16* __restrict__ o, int n) {
  int i = blockIdx.x * 256 + threadIdx.x;
  if (i >= n) return;
  o[i] = f2bf(x[i]);
}

// ----------------- generic C = A * B^T GEMM (K=512 fixed) ------------------
// A[M][512], B[N][512] row-major bf16 (optionally hi/lo split -> 3-term MFMA).
// OUT_MODE: 0 = bf16 hi+lo pair, 1 = bf16, 2 = fp32.
// grid = (N/64, M/64, Z); block = 256 (4 waves, 16 rows each).
template <int IN_SPLIT, int OUT_MODE>
__global__ __launch_bounds__(256, 2) void gemm_bt(
    const u16* __restrict__ Ahi, const u16* __restrict__ Alo,
    const u16* __restrict__ Bhi, const u16* __restrict__ Blo,
    void* __restrict__ Cout, u16* __restrict__ Clo,
    int ldc, long sAz, long sBz, long sCz) {
  __shared__ u16 sAh[64 * 72];
  __shared__ u16 sAl[IN_SPLIT ? 64 * 72 : 8];
  __shared__ u16 sBh[64 * 72];
  __shared__ u16 sBl[IN_SPLIT ? 64 * 72 : 8];

  const int tid = threadIdx.x;
  const int wave = tid >> 6, lane = tid & 63, quad = lane >> 4, l16 = lane & 15;
  const int bn = blockIdx.x * 64, bm = blockIdx.y * 64, bz = blockIdx.z;

  const u16* Ah = Ahi + (long)bz * sAz;
  const u16* Al = IN_SPLIT ? (Alo + (long)bz * sAz) : nullptr;
  const u16* Bh = Bhi + (long)bz * sBz;
  const u16* Bl = IN_SPLIT ? (Blo + (long)bz * sBz) : nullptr;

  floatx4 zero = {0.f, 0.f, 0.f, 0.f};
  floatx4 acc[4];
#pragma unroll
  for (int nb = 0; nb < 4; nb++) acc[nb] = zero;

  for (int ks = 0; ks < 8; ks++) {  // K = 512 in chunks of 64
    __syncthreads();
#pragma unroll
    for (int i = 0; i < 2; i++) {
      int c = tid + 256 * i;
      int row = c >> 3, cc = c & 7;  // 8 x 16B chunks per 64-elem row
      long ga = (long)(bm + row) * 512 + ks * 64 + cc * 8;
      long gb = (long)(bn + row) * 512 + ks * 64 + cc * 8;
      int la = row * 72 + cc * 8;
      *(int4*)&sAh[la] = *(const int4*)&Ah[ga];
      *(int4*)&sBh[la] = *(const int4*)&Bh[gb];
      if (IN_SPLIT) {
        *(int4*)&sAl[la] = *(const int4*)&Al[ga];
        *(int4*)&sBl[la] = *(const int4*)&Bl[gb];
      }
    }
    __syncthreads();
#pragma unroll
    for (int kk = 0; kk < 2; kk++) {
      int aoff = (wave * 16 + l16) * 72 + kk * 32 + quad * 8;
      short8 ah = *(const short8*)&sAh[aoff];
      short8 al;
      if (IN_SPLIT) al = *(const short8*)&sAl[aoff];
#pragma unroll
      for (int nb = 0; nb < 4; nb++) {
        int boff = (nb * 16 + l16) * 72 + kk * 32 + quad * 8;
        short8 bh = *(const short8*)&sBh[boff];
        acc[nb] = __builtin_amdgcn_mfma_f32_16x16x32_bf16(ah, bh, acc[nb], 0, 0, 0);
        if (IN_SPLIT) {
          short8 bl = *(const short8*)&sBl[boff];
          acc[nb] = __builtin_amdgcn_mfma_f32_16x16x32_bf16(ah, bl, acc[nb], 0, 0, 0);
          acc[nb] = __builtin_amdgcn_mfma_f32_16x16x32_bf16(al, bh, acc[nb], 0, 0, 0);
        }
      }
    }
  }

#pragma unroll
  for (int nb = 0; nb < 4; nb++) {
#pragma unroll
    for (int rr = 0; rr < 4; rr++) {
      int row = bm + wave * 16 + quad * 4 + rr;
      int col = bn + nb * 16 + l16;
      long idx = (long)bz * sCz + (long)row * ldc + col;
      float v = acc[nb][rr];
      if (OUT_MODE == 0) {
        u16 h = f2bf(v);
        ((u16*)Cout)[idx] = h;
        Clo[idx] = f2bf(v - bf2f(h));
      } else if (OUT_MODE == 1) {
        ((u16*)Cout)[idx] = f2bf(v);
      } else {
        ((float*)Cout)[idx] = v;
      }
    }
  }
}

// ----------------- flash attention ------------------------------------------
// grid (64 q-tiles, 4 batches); block 256 = 4 waves x 16 query rows.
// Key tiles of 32; QK^T with 3-term hi/lo split; online softmax fp32.
__global__ __launch_bounds__(256, 1) void attn_kernel(
    const u16* __restrict__ Qhi_g, const u16* __restrict__ Qlo_g,
    const u16* __restrict__ Khi_g, const u16* __restrict__ Klo_g,
    const u16* __restrict__ VpT, u16* __restrict__ Ob) {
  __shared__ u16 sKh[32 * 136];   // [32 keys][128 k-chunk] pad->136
  __shared__ u16 sKl[32 * 136];
  __shared__ u16 sV[512 * 40];    // VpT tile [512 dv][32 keys] pad->40
  __shared__ u16 sP[4 * 16 * 40]; // per-wave P [16 q][32 keys] pad->40

  const int tid = threadIdx.x;
  const int wave = tid >> 6, lane = tid & 63, quad = lane >> 4, l16 = lane & 15;
  const int qt = blockIdx.x, b = blockIdx.y;
  const int q0 = qt * 64 + wave * 16;  // wave's first query row (in batch)
  const long qbase = (long)b * L_SEQ + q0;

  // Q fragments (A-layout: lane&15 = row, k = quad*8 + j), resident in regs.
  short8 qhi[16], qlo[16];
#pragma unroll
  for (int kkk = 0; kkk < 16; kkk++) {
    long a = (qbase + l16) * 512 + kkk * 32 + quad * 8;
    qhi[kkk] = *(const short8*)&Qhi_g[a];
    qlo[kkk] = *(const short8*)&Qlo_g[a];
  }

  floatx4 zero = {0.f, 0.f, 0.f, 0.f};
  float m_run[4] = {-1e30f, -1e30f, -1e30f, -1e30f};
  float l_run[4] = {0.f, 0.f, 0.f, 0.f};
  floatx4 oacc[32];
#pragma unroll
  for (int nb = 0; nb < 32; nb++) oacc[nb] = zero;

  const int ktn = 2 * qt + 2;  // key tiles of 32 needed (keys <= qt*64+62)
  for (int u = 0; u < ktn; u++) {
    const int j0 = u * 32;
    floatx4 sacc0 = zero, sacc1 = zero;

    // ---- S = Qh Kh^T (3-term split), dh=512 staged in 4 chunks of 128 ----
#pragma unroll
    for (int st = 0; st < 4; st++) {
      __syncthreads();
#pragma unroll
      for (int i = 0; i < 2; i++) {
        int c = tid + 256 * i;
        int row = c >> 4, cc = c & 15;  // 16 x 16B chunks per 128-elem row
        long g = ((long)b * L_SEQ + j0 + row) * 512 + st * 128 + cc * 8;
        int la = row * 136 + cc * 8;
        *(int4*)&sKh[la] = *(const int4*)&Khi_g[g];
        *(int4*)&sKl[la] = *(const int4*)&Klo_g[g];
      }
      __syncthreads();
#pragma unroll
      for (int kk = 0; kk < 4; kk++) {
        short8 ah = qhi[st * 4 + kk], al = qlo[st * 4 + kk];
        int off = kk * 32 + quad * 8;
        short8 bh0 = *(const short8*)&sKh[l16 * 136 + off];
        short8 bl0 = *(const short8*)&sKl[l16 * 136 + off];
        short8 bh1 = *(const short8*)&sKh[(16 + l16) * 136 + off];
        short8 bl1 = *(const short8*)&sKl[(16 + l16) * 136 + off];
        sacc0 = __builtin_amdgcn_mfma_f32_16x16x32_bf16(ah, bh0, sacc0, 0, 0, 0);
        sacc0 = __builtin_amdgcn_mfma_f32_16x16x32_bf16(ah, bl0, sacc0, 0, 0, 0);
        sacc0 = __builtin_amdgcn_mfma_f32_16x16x32_bf16(al, bh0, sacc0, 0, 0, 0);
        sacc1 = __builtin_amdgcn_mfma_f32_16x16x32_bf16(ah, bh1, sacc1, 0, 0, 0);
        sacc1 = __builtin_amdgcn_mfma_f32_16x16x32_bf16(ah, bl1, sacc1, 0, 0, 0);
        sacc1 = __builtin_amdgcn_mfma_f32_16x16x32_bf16(al, bh1, sacc1, 0, 0, 0);
      }
    }

    // ---- online softmax (fp32); C/D layout: col=lane&15, row=quad*4+rr ----
    float alpha[4];
    bool anyresc = false;
#pragma unroll
    for (int rr = 0; rr < 4; rr++) {
      int irow = q0 + quad * 4 + rr;
      float s0 = sacc0[rr] * SCALE;
      float s1 = sacc1[rr] * SCALE;
      if (j0 + l16 >= irow) s0 = -1e30f;       // strict causal: mask j >= i
      if (j0 + 16 + l16 >= irow) s1 = -1e30f;
      float mx = fmaxf(s0, s1);
      mx = fmaxf(mx, __shfl_xor(mx, 1));
      mx = fmaxf(mx, __shfl_xor(mx, 2));
      mx = fmaxf(mx, __shfl_xor(mx, 4));
      mx = fmaxf(mx, __shfl_xor(mx, 8));
      float mnew = fmaxf(m_run[rr], mx);
      float al_ = __expf(m_run[rr] - mnew);
      float p0 = __expf(s0 - mnew);
      float p1 = __expf(s1 - mnew);
      float ps = p0 + p1;
      ps += __shfl_xor(ps, 1);
      ps += __shfl_xor(ps, 2);
      ps += __shfl_xor(ps, 4);
      ps += __shfl_xor(ps, 8);
      l_run[rr] = l_run[rr] * al_ + ps;
      m_run[rr] = mnew;
      alpha[rr] = al_;
      anyresc |= (al_ != 1.0f);
      int pb = wave * 640 + (quad * 4 + rr) * 40;
      sP[pb + l16] = f2bf(p0);
      sP[pb + 16 + l16] = f2bf(p1);
    }
    if (__any((int)anyresc)) {
#pragma unroll
      for (int nb = 0; nb < 32; nb++) {
        oacc[nb][0] *= alpha[0];
        oacc[nb][1] *= alpha[1];
        oacc[nb][2] *= alpha[2];
        oacc[nb][3] *= alpha[3];
      }
    }

    // ---- stage VpT tile [512 dv][32 keys] ----
#pragma unroll
    for (int i = 0; i < 8; i++) {
      int c = tid + 256 * i;
      int row = c >> 2, cc = c & 3;  // 4 x 16B chunks per 32-elem row
      long g = (long)b * (512L * L_SEQ) + (long)row * L_SEQ + j0 + cc * 8;
      *(int4*)&sV[row * 40 + cc * 8] = *(const int4*)&VpT[g];
    }
    __syncthreads();

    // ---- O += P V : P via LDS round-trip into A-layout ----
    short8 ap = *(const short8*)&sP[wave * 640 + l16 * 40 + quad * 8];
#pragma unroll
    for (int nb = 0; nb < 32; nb++) {
      short8 bv = *(const short8*)&sV[(nb * 16 + l16) * 40 + quad * 8];
      oacc[nb] = __builtin_amdgcn_mfma_f32_16x16x32_bf16(ap, bv, oacc[nb], 0, 0, 0);
    }
    // next iteration's first __syncthreads() protects sKh/sV reuse
  }

  // ---- epilogue: normalize, zero row 0, store bf16 O ----
#pragma unroll
  for (int rr = 0; rr < 4; rr++) {
    int irow = q0 + quad * 4 + rr;
    float inv = (irow == 0 || l_run[rr] <= 0.f) ? 0.f : 1.0f / l_run[rr];
    long obase = ((long)b * L_SEQ + irow) * 512;
#pragma unroll
    for (int nb = 0; nb < 32; nb++) {
      Ob[obase + nb * 16 + l16] = f2bf(oacc[nb][rr] * inv);
    }
  }
}

// ---------------------------------------------------------------------------
extern "C" void kernel_launch(void* const* d_in, const int* in_sizes, int n_in,
                              void* d_out, int out_size, void* d_ws, size_t ws_size,
                              hipStream_t stream) {
  const float* K  = (const float*)d_in[0];
  const float* V  = (const float*)d_in[1];
  const float* Wq = (const float*)d_in[2];
  const float* Wk = (const float*)d_in[3];
  const float* Wv = (const float*)d_in[4];
  const float* Wo = (const float*)d_in[5];
  float* out = (float*)d_out;

  const int NKV = NBATCH * L_SEQ * DMODEL;  // 8,388,608
  const int NW = DMODEL * DMODEL;           // 262,144

  // workspace carve (needs ~147 MB)
  char* w = (char*)d_ws;
  size_t off = 0;
  auto carve = [&](size_t bytes) {
    void* p = w + off;
    off += (bytes + 255) & ~(size_t)255;
    return p;
  };
  u16* Khi  = (u16*)carve((size_t)NKV * 2);
  u16* Klo  = (u16*)carve((size_t)NKV * 2);
  u16* Vb   = (u16*)carve((size_t)NKV * 2);
  u16* Qhhi = (u16*)carve((size_t)NKV * 2);
  u16* Qhlo = (u16*)carve((size_t)NKV * 2);
  u16* Khhi = (u16*)carve((size_t)NKV * 2);
  u16* Khlo = (u16*)carve((size_t)NKV * 2);
  u16* VpTw = (u16*)carve((size_t)NKV * 2);
  u16* Obw  = (u16*)carve((size_t)NKV * 2);
  u16* Wqhi = (u16*)carve((size_t)NW * 2);
  u16* Wqlo = (u16*)carve((size_t)NW * 2);
  u16* Wkhi = (u16*)carve((size_t)NW * 2);
  u16* Wklo = (u16*)carve((size_t)NW * 2);
  u16* Wvb  = (u16*)carve((size_t)NW * 2);
  u16* Wob  = (u16*)carve((size_t)NW * 2);

  // 1) converts
  split_f32<<<NKV / 256, 256, 0, stream>>>(K, Khi, Klo, NKV);
  split_f32<<<NW / 256, 256, 0, stream>>>(Wq, Wqhi, Wqlo, NW);
  split_f32<<<NW / 256, 256, 0, stream>>>(Wk, Wkhi, Wklo, NW);
  cvt_f32<<<NKV / 256, 256, 0, stream>>>(V, Vb, NKV);
  cvt_f32<<<NW / 256, 256, 0, stream>>>(Wv, Wvb, NW);
  cvt_f32<<<NW / 256, 256, 0, stream>>>(Wo, Wob, NW);

  // 2) Qh = K Wq^T, Kh = K Wk^T  (split in, hi/lo out)  M=16384, N=512
  gemm_bt<1, 0><<<dim3(8, 256, 1), 256, 0, stream>>>(
      Khi, Klo, Wqhi, Wqlo, (void*)Qhhi, Qhlo, 512, 0, 0, 0);
  gemm_bt<1, 0><<<dim3(8, 256, 1), 256, 0, stream>>>(
      Khi, Klo, Wkhi, Wklo, (void*)Khhi, Khlo, 512, 0, 0, 0);

  // 3) VpT_b = Wv V_b^T : M=512 (dv), N=4096 (seq), per batch (z)
  gemm_bt<0, 1><<<dim3(64, 8, NBATCH), 256, 0, stream>>>(
      Wvb, nullptr, Vb, nullptr, (void*)VpTw, nullptr,
      L_SEQ, 0, (long)L_SEQ * 512, (long)512 * L_SEQ);

  // 4) flash attention -> Ob (bf16)
  attn_kernel<<<dim3(64, NBATCH, 1), 256, 0, stream>>>(
      Qhhi, Qhlo, Khhi, Khlo, VpTw, Obw);

  // 5) Vhat = Ob Wo^T -> fp32 d_out   M=16384, N=512
  gemm_bt<0, 2><<<dim3(8, 256, 1), 256, 0, stream>>>(
      Obw, nullptr, Wob, nullptr, (void*)out, nullptr, 512, 0, 0, 0);

  (void)in_sizes; (void)n_in; (void)out_size; (void)ws_size;
}